// Round 4
// baseline (302.726 us; speedup 1.0000x reference)
//
#include <hip/hip_runtime.h>
#include <cstddef>
#include <cstdint>

// Problem constants
#define Bb   32
#define Ss   512
#define Dd   768
#define Ww   256
#define Pp   1024
#define NH   300          // hidden
#define NPAD 640          // padded N (600 real + 40 zero)
#define Mm   (Bb * Ww)    // 8192 words
#define NBLK 320          // grid size == number of GEMM tiles (64 M x 5 N)
#define NTHR 256

typedef __attribute__((ext_vector_type(8))) short bf16x8;
typedef __attribute__((ext_vector_type(4))) float f32x4;

#define GPTR(p) ((const __attribute__((address_space(1))) void*)(p))
#define LPTR(p) ((__attribute__((address_space(3))) void*)(p))

__device__ __forceinline__ unsigned short f2bf(float x) {
    unsigned u = __builtin_bit_cast(unsigned, x);
    u += 0x7fffu + ((u >> 16) & 1u);          // RNE
    return (unsigned short)(u >> 16);
}
__device__ __forceinline__ float bf2f(unsigned short u) {
    return __builtin_bit_cast(float, (unsigned)u << 16);
}
__device__ __forceinline__ float fast_tanh(float x) {
    // tanh(x) = 1 - 2/(exp(2x)+1); |x| clamped so exp never overflows
    x = fminf(fmaxf(x, -15.0f), 15.0f);
    float e = __expf(2.0f * x);
    return 1.0f - 2.0f * __builtin_amdgcn_rcpf(e + 1.0f);
}

// device-scope grid barrier (all NBLK blocks co-resident via launch_bounds)
__device__ __forceinline__ void grid_barrier(int* cnt) {
    __syncthreads();
    if (threadIdx.x == 0) {
        __threadfence();   // release our global writes (device scope)
        __hip_atomic_fetch_add(cnt, 1, __ATOMIC_ACQ_REL, __HIP_MEMORY_SCOPE_AGENT);
        while (__hip_atomic_load(cnt, __ATOMIC_ACQUIRE, __HIP_MEMORY_SCOPE_AGENT) < NBLK)
            __builtin_amdgcn_s_sleep(4);
        __threadfence();   // acquire: invalidate caches before reading others' data
    }
    __syncthreads();
}

// -------------------------------------------------------------------------
// One persistent kernel, 320 blocks x 256 threads, 3 phases + 2 grid barriers.
//   A: pool h -> emb (bf16), repack w1 -> bmatT (bf16, N-transposed, padded)
//   B: MFMA GEMM proj[8192][640] = emb @ Bmat  (128x128 tile per block,
//      BK=32, double-buffered LDS, 1 barrier per K-step)
//   C: per-pair tanh + 300x4 matvec + softmax (1 wave per pair, grid-stride)
// -------------------------------------------------------------------------
__global__ __launch_bounds__(NTHR, 2) void bert_fused_kernel(
    const float* __restrict__ h, const float* __restrict__ w1,
    const float* __restrict__ b1, const float* __restrict__ w2,
    const float* __restrict__ b2,
    const int* __restrict__ word_start, const int* __restrict__ word_len,
    const int* __restrict__ pair_idx,
    unsigned short* __restrict__ emb, unsigned short* __restrict__ bmatT,
    unsigned short* __restrict__ proj, int* __restrict__ barrier_cnt,
    float* __restrict__ out)
{
    __shared__ bf16x8 Al[2][4][128];   // 16 KB (double-buffered A tile)
    __shared__ bf16x8 Bl[2][4][128];   // 16 KB

    const int bid = blockIdx.x;
    const int t   = threadIdx.x;
    const int gid = bid * NTHR + t;

    // ============================ Phase A ================================
    // pool: 8192 words x 192 float4 chunks
    for (int u = gid; u < Mm * 192; u += NBLK * NTHR) {
        const int m = u / 192;
        const int c = u - m * 192;
        const int b   = m >> 8;
        const int s0  = word_start[m];
        const int len = word_len[m];
        const float* p = h + (size_t)b * (Ss * Dd) + (size_t)s0 * Dd + c * 4;
        float4 v = *(const float4*)p;
        if (len == 2) {
            float4 v2 = *(const float4*)(p + Dd);
            v.x = (v.x + v2.x) * 0.5f;
            v.y = (v.y + v2.y) * 0.5f;
            v.z = (v.z + v2.z) * 0.5f;
            v.w = (v.w + v2.w) * 0.5f;
        }
        ushort4 o = make_ushort4(f2bf(v.x), f2bf(v.y), f2bf(v.z), f2bf(v.w));
        *(ushort4*)(emb + (size_t)m * Dd + c * 4) = o;
    }
    // repack: BmatT[n][k], coalesced w1 reads (lane = consecutive n)
    for (int u = gid; u < Dd * NPAD; u += NBLK * NTHR) {   // exactly 6 iters
        const int k = u / NPAD;
        const int n = u - k * NPAD;
        float v = 0.0f;
        if (n < NH)          v = w1[(size_t)k * NH + n];
        else if (n < 2 * NH) v = w1[(size_t)(Dd + k) * NH + (n - NH)];
        bmatT[(size_t)n * Dd + k] = f2bf(v);
    }

    grid_barrier(barrier_cnt + 0);

    // ============================ Phase B ================================
    {
        // bijective XCD swizzle: 320 = 8 XCDs x 40
        const int swz   = (bid & 7) * 40 + (bid >> 3);
        const int mBase = (swz / 5) * 128;
        const int nBase = (swz % 5) * 128;

        const int srow = t & 127;
        const int skb  = t >> 7;
        const unsigned short* srcA = emb   + (size_t)(mBase + srow) * Dd + (skb << 3);
        const unsigned short* srcB = bmatT + (size_t)(nBase + srow) * Dd + (skb << 3);
        char* ldsA = (char*)&Al[0][0][0] + t * 16;
        char* ldsB = (char*)&Bl[0][0][0] + t * 16;

        const int lane = t & 63;
        const int w    = t >> 6;
        const int wr   = w >> 1;
        const int wc   = w & 1;
        const int fr   = lane & 15;
        const int kb   = lane >> 4;

        f32x4 acc[4][4];
#pragma unroll
        for (int i = 0; i < 4; ++i)
#pragma unroll
            for (int j = 0; j < 4; ++j)
#pragma unroll
                for (int r = 0; r < 4; ++r) acc[i][j][r] = 0.0f;

#define STAGE(c, off)                                                                          \
        __builtin_amdgcn_global_load_lds(GPTR(srcA + (off)),      LPTR(ldsA + (c) * 8192),        16, 0, 0); \
        __builtin_amdgcn_global_load_lds(GPTR(srcA + (off) + 16), LPTR(ldsA + (c) * 8192 + 4096), 16, 0, 0); \
        __builtin_amdgcn_global_load_lds(GPTR(srcB + (off)),      LPTR(ldsB + (c) * 8192),        16, 0, 0); \
        __builtin_amdgcn_global_load_lds(GPTR(srcB + (off) + 16), LPTR(ldsB + (c) * 8192 + 4096), 16, 0, 0)

#define COMPUTE(c)                                                                             \
        {                                                                                      \
            bf16x8 a[4], b[4];                                                                 \
            _Pragma("unroll")                                                                  \
            for (int mi = 0; mi < 4; ++mi) a[mi] = Al[c][kb][wr * 64 + mi * 16 + fr];          \
            _Pragma("unroll")                                                                  \
            for (int ni = 0; ni < 4; ++ni) b[ni] = Bl[c][kb][wc * 64 + ni * 16 + fr];          \
            _Pragma("unroll")                                                                  \
            for (int mi = 0; mi < 4; ++mi)                                                     \
                _Pragma("unroll")                                                              \
                for (int ni = 0; ni < 4; ++ni)                                                 \
                    acc[mi][ni] = __builtin_amdgcn_mfma_f32_16x16x32_bf16(a[mi], b[ni], acc[mi][ni], 0, 0, 0); \
        }

        STAGE(0, 0);
        __syncthreads();                 // vmcnt(0) drain + barrier: buf0 ready
        int cur = 0;
        for (int k0 = 32; k0 < Dd; k0 += 32) {
            STAGE(cur ^ 1, k0);          // next tile loads fly under compute
            COMPUTE(cur);
            __syncthreads();             // drains vmcnt(0): next buf ready, cur reusable
            cur ^= 1;
        }
        COMPUTE(cur);
#undef STAGE
#undef COMPUTE

        // C/D layout: col = lane&15, row = (lane>>4)*4 + r
        const int r0 = mBase + wr * 64 + kb * 4;
        const int c0 = nBase + wc * 64 + fr;
#pragma unroll
        for (int mi = 0; mi < 4; ++mi)
#pragma unroll
            for (int ni = 0; ni < 4; ++ni)
#pragma unroll
                for (int r = 0; r < 4; ++r)
                    proj[(size_t)(r0 + mi * 16 + r) * NPAD + c0 + ni * 16] = f2bf(acc[mi][ni][r]);
    }

    grid_barrier(barrier_cnt + 1);

    // ============================ Phase C ================================
    {
        const int wl   = t >> 6;
        const int lane = t & 63;

        // hoist b1 / w2 fragments (constant per lane across all pairs)
        float  b1r[5];
        float4 w2r[5];
#pragma unroll
        for (int it = 0; it < 5; ++it) {
            const int j = lane + it * 64;
            if (j < NH) {
                b1r[it] = b1[j];
                w2r[it] = *(const float4*)(w2 + (size_t)j * 4);
            } else {
                b1r[it] = 0.0f;
                w2r[it] = make_float4(0.f, 0.f, 0.f, 0.f);
            }
        }
        const float bb0 = b2[0], bb1 = b2[1], bb2 = b2[2], bb3 = b2[3];

        for (int wid = bid * 4 + wl; wid < Bb * Pp; wid += NBLK * 4) {
            const int b  = wid >> 10;
            const int i0 = pair_idx[wid * 2 + 0];
            const int i1 = pair_idx[wid * 2 + 1];
            const unsigned short* r0 = (i0 >= 0) ? proj + ((size_t)(b * Ww + i0) * NPAD)      : nullptr;
            const unsigned short* r1 = (i1 >= 0) ? proj + ((size_t)(b * Ww + i1) * NPAD + NH) : nullptr;

            float a0 = 0.f, a1 = 0.f, a2 = 0.f, a3 = 0.f;
#pragma unroll
            for (int it = 0; it < 5; ++it) {
                const int j = lane + it * 64;
                if (j < NH) {
                    float v = b1r[it];
                    if (r0) v += bf2f(r0[j]);
                    if (r1) v += bf2f(r1[j]);
                    const float x = fast_tanh(v);
                    a0 = fmaf(x, w2r[it].x, a0);
                    a1 = fmaf(x, w2r[it].y, a1);
                    a2 = fmaf(x, w2r[it].z, a2);
                    a3 = fmaf(x, w2r[it].w, a3);
                }
            }
#pragma unroll
            for (int off = 32; off >= 1; off >>= 1) {
                a0 += __shfl_xor(a0, off, 64);
                a1 += __shfl_xor(a1, off, 64);
                a2 += __shfl_xor(a2, off, 64);
                a3 += __shfl_xor(a3, off, 64);
            }
            if (lane == 0) {
                const float l0 = a0 + bb0, l1 = a1 + bb1, l2 = a2 + bb2, l3 = a3 + bb3;
                const float mx = fmaxf(fmaxf(l0, l1), fmaxf(l2, l3));
                const float e0 = __expf(l0 - mx), e1 = __expf(l1 - mx);
                const float e2 = __expf(l2 - mx), e3 = __expf(l3 - mx);
                const float inv = 1.0f / (e0 + e1 + e2 + e3);
                float4 o = {e0 * inv, e1 * inv, e2 * inv, e3 * inv};
                *(float4*)(out + (size_t)wid * 4) = o;
            }
        }
    }
}

// -------------------------------------------------------------------------
extern "C" void kernel_launch(void* const* d_in, const int* in_sizes, int n_in,
                              void* d_out, int out_size, void* d_ws, size_t ws_size,
                              hipStream_t stream)
{
    const float* h          = (const float*)d_in[0];
    const float* w1         = (const float*)d_in[1];
    const float* b1         = (const float*)d_in[2];
    const float* w2         = (const float*)d_in[3];
    const float* b2         = (const float*)d_in[4];
    const int*   word_start = (const int*)d_in[5];
    const int*   word_len   = (const int*)d_in[6];
    const int*   pair_idx   = (const int*)d_in[7];
    float*       out        = (float*)d_out;

    // workspace layout
    unsigned short* proj  = (unsigned short*)d_ws;                          // 10,485,760 B
    unsigned short* emb   = (unsigned short*)((char*)d_ws + 10485760);      // 12,582,912 B
    unsigned short* bmatT = (unsigned short*)((char*)d_ws + 10485760 + 12582912); // 983,040 B
    int*            bcnt  = (int*)((char*)d_ws + 33554432);                 // barrier counters

    hipMemsetAsync(bcnt, 0, 256, stream);   // re-zero barrier counters (graph-capturable)
    bert_fused_kernel<<<dim3(NBLK), dim3(NTHR), 0, stream>>>(
        h, w1, b1, w2, b2, word_start, word_len, pair_idx,
        emb, bmatT, proj, bcnt, out);
}

// Round 5
// 106.746 us; speedup vs baseline: 2.8359x; 2.8359x over previous
//
#include <hip/hip_runtime.h>
#include <cstddef>
#include <cstdint>

// Problem constants
#define Bb   32
#define Ss   512
#define Dd   768
#define Ww   256
#define Pp   1024
#define NH   300          // hidden
#define NPAD 640          // padded N (600 real + 40 zero)
#define Mm   (Bb * Ww)    // 8192 words

typedef __attribute__((ext_vector_type(8))) short bf16x8;
typedef __attribute__((ext_vector_type(4))) float f32x4;

#define GPTR(p) ((const __attribute__((address_space(1))) void*)(p))
#define LPTR(p) ((__attribute__((address_space(3))) void*)(p))

__device__ __forceinline__ unsigned short f2bf(float x) {
    unsigned u = __builtin_bit_cast(unsigned, x);
    u += 0x7fffu + ((u >> 16) & 1u);          // RNE
    return (unsigned short)(u >> 16);
}
__device__ __forceinline__ float bf2f(unsigned short u) {
    return __builtin_bit_cast(float, (unsigned)u << 16);
}
__device__ __forceinline__ float fast_tanh(float x) {
    // tanh(x) = 1 - 2/(exp(2x)+1); clamp so exp never overflows
    x = fminf(fmaxf(x, -15.0f), 15.0f);
    float e = __expf(2.0f * x);
    return 1.0f - 2.0f * __builtin_amdgcn_rcpf(e + 1.0f);
}

// -------------------------------------------------------------------------
// Kernel 1 (prep): blocks [0, 8192): mean-pool h -> emb bf16 (one word/block)
//                  blocks [8192, 8192+2560): repack w1 -> BmatT bf16
//   BmatT[n][k] = n<300 ? w1[k][n] : (n<600 ? w1[768+k][n-300] : 0)
// -------------------------------------------------------------------------
__global__ __launch_bounds__(192) void prep_kernel(
    const float* __restrict__ h, const float* __restrict__ w1,
    const int* __restrict__ word_start, const int* __restrict__ word_len,
    unsigned short* __restrict__ emb, unsigned short* __restrict__ bmatT)
{
    const int bid = blockIdx.x;
    const int t   = threadIdx.x;      // 0..191
    if (bid < Mm) {
        const int m   = bid;
        const int b   = m >> 8;
        const int s0  = word_start[m];
        const int len = word_len[m];
        const float* p = h + (size_t)b * (Ss * Dd) + (size_t)s0 * Dd + t * 4;
        float4 v = *(const float4*)p;
        if (len == 2) {
            float4 v2 = *(const float4*)(p + Dd);
            v.x = (v.x + v2.x) * 0.5f;
            v.y = (v.y + v2.y) * 0.5f;
            v.z = (v.z + v2.z) * 0.5f;
            v.w = (v.w + v2.w) * 0.5f;
        }
        ushort4 o = make_ushort4(f2bf(v.x), f2bf(v.y), f2bf(v.z), f2bf(v.w));
        *(ushort4*)(emb + (size_t)m * Dd + t * 4) = o;
    } else {
        const int rb = bid - Mm;
        const int n  = rb >> 2;                 // 0..639
        const int k  = ((rb & 3) * 192) + t;    // 0..767
        float v = 0.0f;
        if (n < NH)            v = w1[(size_t)k * NH + n];
        else if (n < 2 * NH)   v = w1[(size_t)(Dd + k) * NH + (n - NH)];
        bmatT[(size_t)n * Dd + k] = f2bf(v);
    }
}

// -------------------------------------------------------------------------
// Kernel 2: MFMA bf16 GEMM: proj[8192][640] = emb[8192][768] @ Bmat[768][640]
// Tile 128x128, BK=32, 256 threads = 4 waves (2x2), each wave 64x64 (4x4).
// Double-buffered LDS (2-phase): STAGE(next) issued before COMPUTE(cur),
// single __syncthreads (vmcnt(0)+barrier) per K-step.
// Bijective XCD swizzle over the 320-block grid (320 = 8*40).
// -------------------------------------------------------------------------
__global__ __launch_bounds__(256) void gemm_kernel(
    const unsigned short* __restrict__ emb, const unsigned short* __restrict__ bmatT,
    unsigned short* __restrict__ proj)
{
    __shared__ bf16x8 Al[2][4][128];   // 16 KB
    __shared__ bf16x8 Bl[2][4][128];   // 16 KB

    const int bid = blockIdx.x;
    const int t   = threadIdx.x;

    // bijective XCD swizzle: 320 blocks, 8 XCDs, 40 per chunk
    const int swz   = (bid & 7) * 40 + (bid >> 3);
    const int mBase = (swz / 5) * 128;
    const int nBase = (swz % 5) * 128;

    const int srow = t & 127;
    const int skb  = t >> 7;
    const unsigned short* srcA = emb   + (size_t)(mBase + srow) * Dd + (skb << 3);
    const unsigned short* srcB = bmatT + (size_t)(nBase + srow) * Dd + (skb << 3);
    char* ldsA = (char*)&Al[0][0][0] + t * 16;
    char* ldsB = (char*)&Bl[0][0][0] + t * 16;

    const int lane = t & 63;
    const int w    = t >> 6;
    const int wr   = w >> 1;
    const int wc   = w & 1;
    const int fr   = lane & 15;
    const int kb   = lane >> 4;

    f32x4 acc[4][4];
#pragma unroll
    for (int i = 0; i < 4; ++i)
#pragma unroll
        for (int j = 0; j < 4; ++j)
#pragma unroll
            for (int r = 0; r < 4; ++r) acc[i][j][r] = 0.0f;

#define STAGE(c, off)                                                                          \
    __builtin_amdgcn_global_load_lds(GPTR(srcA + (off)),      LPTR(ldsA + (c) * 8192),        16, 0, 0); \
    __builtin_amdgcn_global_load_lds(GPTR(srcA + (off) + 16), LPTR(ldsA + (c) * 8192 + 4096), 16, 0, 0); \
    __builtin_amdgcn_global_load_lds(GPTR(srcB + (off)),      LPTR(ldsB + (c) * 8192),        16, 0, 0); \
    __builtin_amdgcn_global_load_lds(GPTR(srcB + (off) + 16), LPTR(ldsB + (c) * 8192 + 4096), 16, 0, 0)

#define COMPUTE(c)                                                                             \
    {                                                                                          \
        bf16x8 a[4], b[4];                                                                     \
        _Pragma("unroll")                                                                      \
        for (int mi = 0; mi < 4; ++mi) a[mi] = Al[c][kb][wr * 64 + mi * 16 + fr];              \
        _Pragma("unroll")                                                                      \
        for (int ni = 0; ni < 4; ++ni) b[ni] = Bl[c][kb][wc * 64 + ni * 16 + fr];              \
        _Pragma("unroll")                                                                      \
        for (int mi = 0; mi < 4; ++mi)                                                         \
            _Pragma("unroll")                                                                  \
            for (int ni = 0; ni < 4; ++ni)                                                     \
                acc[mi][ni] = __builtin_amdgcn_mfma_f32_16x16x32_bf16(a[mi], b[ni], acc[mi][ni], 0, 0, 0); \
    }

    STAGE(0, 0);
    __syncthreads();                 // vmcnt(0) drain + barrier: buf0 ready
    int cur = 0;
    for (int k0 = 32; k0 < Dd; k0 += 32) {
        STAGE(cur ^ 1, k0);          // next-tile loads fly under compute
        COMPUTE(cur);
        __syncthreads();             // drains vmcnt(0): next buf ready, cur reusable
        cur ^= 1;
    }
    COMPUTE(cur);
#undef STAGE
#undef COMPUTE

    // C/D layout: col = lane&15, row = (lane>>4)*4 + r   [verified m89/m91]
    const int r0 = mBase + wr * 64 + kb * 4;
    const int c0 = nBase + wc * 64 + fr;
#pragma unroll
    for (int mi = 0; mi < 4; ++mi)
#pragma unroll
        for (int ni = 0; ni < 4; ++ni)
#pragma unroll
            for (int r = 0; r < 4; ++r)
                proj[(size_t)(r0 + mi * 16 + r) * NPAD + c0 + ni * 16] = f2bf(acc[mi][ni][r]);
}

// -------------------------------------------------------------------------
// Kernel 3: per-pair tanh + 300x4 matvec + softmax. One wave per pair,
// XCD-local batch mapping: XCD x handles batches [4x, 4x+4) so the proj
// working set (4 x 327 KB) fits that XCD's 4 MB L2.
// -------------------------------------------------------------------------
__global__ __launch_bounds__(256) void mlp_kernel(
    const unsigned short* __restrict__ proj, const float* __restrict__ b1,
    const float* __restrict__ w2, const float* __restrict__ b2,
    const int* __restrict__ pair_idx, float* __restrict__ out)
{
    const int bid   = blockIdx.x;        // 0..319
    const int t     = threadIdx.x;
    const int xcd   = bid & 7;
    const int chunk = bid >> 3;          // 0..39
    const int wl    = t >> 6;
    const int lane  = t & 63;
    const int slot  = chunk * 4 + wl;    // 0..159

    // hoist b1 / w2 fragments (constant per lane across all pairs)
    float  b1r[5];
    float4 w2r[5];
#pragma unroll
    for (int it = 0; it < 5; ++it) {
        const int j = lane + it * 64;
        if (j < NH) {
            b1r[it] = b1[j];
            w2r[it] = *(const float4*)(w2 + (size_t)j * 4);
        } else {
            b1r[it] = 0.0f;
            w2r[it] = make_float4(0.f, 0.f, 0.f, 0.f);
        }
    }
    const float bb0 = b2[0], bb1 = b2[1], bb2 = b2[2], bb3 = b2[3];

    for (int p = slot; p < 4 * Pp; p += 160) {
        const int wid = (xcd << 12) + p;           // pair id; batch = wid>>10
        const int b   = wid >> 10;
        const int i0  = pair_idx[wid * 2 + 0];
        const int i1  = pair_idx[wid * 2 + 1];
        const unsigned short* r0 = (i0 >= 0) ? proj + ((size_t)(b * Ww + i0) * NPAD)      : nullptr;
        const unsigned short* r1 = (i1 >= 0) ? proj + ((size_t)(b * Ww + i1) * NPAD + NH) : nullptr;

        float a0 = 0.f, a1 = 0.f, a2 = 0.f, a3 = 0.f;
#pragma unroll
        for (int it = 0; it < 5; ++it) {
            const int j = lane + it * 64;
            if (j < NH) {
                float v = b1r[it];
                if (r0) v += bf2f(r0[j]);
                if (r1) v += bf2f(r1[j]);
                const float x = fast_tanh(v);
                a0 = fmaf(x, w2r[it].x, a0);
                a1 = fmaf(x, w2r[it].y, a1);
                a2 = fmaf(x, w2r[it].z, a2);
                a3 = fmaf(x, w2r[it].w, a3);
            }
        }
#pragma unroll
        for (int off = 32; off >= 1; off >>= 1) {
            a0 += __shfl_xor(a0, off, 64);
            a1 += __shfl_xor(a1, off, 64);
            a2 += __shfl_xor(a2, off, 64);
            a3 += __shfl_xor(a3, off, 64);
        }
        if (lane == 0) {
            const float l0 = a0 + bb0, l1 = a1 + bb1, l2 = a2 + bb2, l3 = a3 + bb3;
            const float mx = fmaxf(fmaxf(l0, l1), fmaxf(l2, l3));
            const float e0 = __expf(l0 - mx), e1 = __expf(l1 - mx);
            const float e2 = __expf(l2 - mx), e3 = __expf(l3 - mx);
            const float inv = 1.0f / (e0 + e1 + e2 + e3);
            float4 o = {e0 * inv, e1 * inv, e2 * inv, e3 * inv};
            *(float4*)(out + (size_t)wid * 4) = o;
        }
    }
}

// -------------------------------------------------------------------------
extern "C" void kernel_launch(void* const* d_in, const int* in_sizes, int n_in,
                              void* d_out, int out_size, void* d_ws, size_t ws_size,
                              hipStream_t stream)
{
    const float* h          = (const float*)d_in[0];
    const float* w1         = (const float*)d_in[1];
    const float* b1         = (const float*)d_in[2];
    const float* w2         = (const float*)d_in[3];
    const float* b2         = (const float*)d_in[4];
    const int*   word_start = (const int*)d_in[5];
    const int*   word_len   = (const int*)d_in[6];
    const int*   pair_idx   = (const int*)d_in[7];
    float*       out        = (float*)d_out;

    // workspace layout (all bf16)
    unsigned short* proj  = (unsigned short*)d_ws;                        // 10,485,760 B
    unsigned short* emb   = (unsigned short*)((char*)d_ws + 10485760);    // 12,582,912 B
    unsigned short* bmatT = (unsigned short*)((char*)d_ws + 10485760 + 12582912); // 983,040 B

    prep_kernel<<<dim3(Mm + 4 * NPAD), dim3(192), 0, stream>>>(h, w1, word_start, word_len, emb, bmatT);
    gemm_kernel<<<dim3(320), dim3(256), 0, stream>>>(emb, bmatT, proj);
    mlp_kernel <<<dim3(320), dim3(256), 0, stream>>>(proj, b1, w2, b2, pair_idx, out);
}

// Round 6
// 63.875 us; speedup vs baseline: 4.7394x; 1.6712x over previous
//
#include <hip/hip_runtime.h>
#include <cstddef>
#include <cstdint>

// Problem constants
#define Bb   32
#define Ss   512
#define Dd   768
#define Ww   256
#define Pp   1024
#define NH   300          // hidden
#define NPAD 640          // padded N (600 real + 40 zero)
#define Mm   (Bb * Ww)    // 8192 words

typedef __attribute__((ext_vector_type(8))) short bf16x8;
typedef __attribute__((ext_vector_type(4))) float f32x4;

#define GPTR(p) ((const __attribute__((address_space(1))) void*)(p))
#define LPTR(p) ((__attribute__((address_space(3))) void*)(p))

__device__ __forceinline__ unsigned short f2bf(float x) {
    unsigned u = __builtin_bit_cast(unsigned, x);
    u += 0x7fffu + ((u >> 16) & 1u);          // RNE
    return (unsigned short)(u >> 16);
}
__device__ __forceinline__ float bf2f(unsigned short u) {
    return __builtin_bit_cast(float, (unsigned)u << 16);
}
__device__ __forceinline__ float fast_tanh(float x) {
    // tanh(x) = 1 - 2/(exp(2x)+1); clamp so exp never overflows
    x = fminf(fmaxf(x, -15.0f), 15.0f);
    float e = __expf(2.0f * x);
    return 1.0f - 2.0f * __builtin_amdgcn_rcpf(e + 1.0f);
}

// -------------------------------------------------------------------------
// Kernel 1 (prep): blocks [0, 8192): mean-pool h -> emb bf16 (one word/block)
//                  blocks [8192, 8192+2560): repack w1 -> BmatT bf16
//   BmatT[n][k] = n<300 ? w1[k][n] : (n<600 ? w1[768+k][n-300] : 0)
// -------------------------------------------------------------------------
__global__ __launch_bounds__(192) void prep_kernel(
    const float* __restrict__ h, const float* __restrict__ w1,
    const int* __restrict__ word_start, const int* __restrict__ word_len,
    unsigned short* __restrict__ emb, unsigned short* __restrict__ bmatT)
{
    const int bid = blockIdx.x;
    const int t   = threadIdx.x;      // 0..191
    if (bid < Mm) {
        const int m   = bid;
        const int b   = m >> 8;
        const int s0  = word_start[m];
        const int len = word_len[m];
        const float* p = h + (size_t)b * (Ss * Dd) + (size_t)s0 * Dd + t * 4;
        float4 v = *(const float4*)p;
        if (len == 2) {
            float4 v2 = *(const float4*)(p + Dd);
            v.x = (v.x + v2.x) * 0.5f;
            v.y = (v.y + v2.y) * 0.5f;
            v.z = (v.z + v2.z) * 0.5f;
            v.w = (v.w + v2.w) * 0.5f;
        }
        ushort4 o = make_ushort4(f2bf(v.x), f2bf(v.y), f2bf(v.z), f2bf(v.w));
        *(ushort4*)(emb + (size_t)m * Dd + t * 4) = o;
    } else {
        const int rb = bid - Mm;
        const int n  = rb >> 2;                 // 0..639
        const int k  = ((rb & 3) * 192) + t;    // 0..767
        float v = 0.0f;
        if (n < NH)            v = w1[(size_t)k * NH + n];
        else if (n < 2 * NH)   v = w1[(size_t)(Dd + k) * NH + (n - NH)];
        bmatT[(size_t)n * Dd + k] = f2bf(v);
    }
}

// -------------------------------------------------------------------------
// Kernel 2: MFMA bf16 GEMM: proj[8192][640] = emb[8192][768] @ Bmat[768][640]
// Tile 128x128, BK=32, 256 threads = 4 waves (2x2), each wave 64x64 (4x4).
// Double-buffered LDS (2-phase): STAGE(next) issued before COMPUTE(cur),
// single __syncthreads (vmcnt(0)+barrier) per K-step.
// Bijective XCD swizzle over the 320-block grid (320 = 8*40).
// -------------------------------------------------------------------------
__global__ __launch_bounds__(256) void gemm_kernel(
    const unsigned short* __restrict__ emb, const unsigned short* __restrict__ bmatT,
    unsigned short* __restrict__ proj)
{
    __shared__ bf16x8 Al[2][4][128];   // 16 KB
    __shared__ bf16x8 Bl[2][4][128];   // 16 KB

    const int bid = blockIdx.x;
    const int t   = threadIdx.x;

    // bijective XCD swizzle: 320 blocks, 8 XCDs, 40 per chunk
    const int swz   = (bid & 7) * 40 + (bid >> 3);
    const int mBase = (swz / 5) * 128;
    const int nBase = (swz % 5) * 128;

    const int srow = t & 127;
    const int skb  = t >> 7;
    const unsigned short* srcA = emb   + (size_t)(mBase + srow) * Dd + (skb << 3);
    const unsigned short* srcB = bmatT + (size_t)(nBase + srow) * Dd + (skb << 3);
    char* ldsA = (char*)&Al[0][0][0] + t * 16;
    char* ldsB = (char*)&Bl[0][0][0] + t * 16;

    const int lane = t & 63;
    const int w    = t >> 6;
    const int wr   = w >> 1;
    const int wc   = w & 1;
    const int fr   = lane & 15;
    const int kb   = lane >> 4;

    f32x4 acc[4][4];
#pragma unroll
    for (int i = 0; i < 4; ++i)
#pragma unroll
        for (int j = 0; j < 4; ++j)
#pragma unroll
            for (int r = 0; r < 4; ++r) acc[i][j][r] = 0.0f;

#define STAGE(c, off)                                                                          \
    __builtin_amdgcn_global_load_lds(GPTR(srcA + (off)),      LPTR(ldsA + (c) * 8192),        16, 0, 0); \
    __builtin_amdgcn_global_load_lds(GPTR(srcA + (off) + 16), LPTR(ldsA + (c) * 8192 + 4096), 16, 0, 0); \
    __builtin_amdgcn_global_load_lds(GPTR(srcB + (off)),      LPTR(ldsB + (c) * 8192),        16, 0, 0); \
    __builtin_amdgcn_global_load_lds(GPTR(srcB + (off) + 16), LPTR(ldsB + (c) * 8192 + 4096), 16, 0, 0)

#define COMPUTE(c)                                                                             \
    {                                                                                          \
        bf16x8 a[4], b[4];                                                                     \
        _Pragma("unroll")                                                                      \
        for (int mi = 0; mi < 4; ++mi) a[mi] = Al[c][kb][wr * 64 + mi * 16 + fr];              \
        _Pragma("unroll")                                                                      \
        for (int ni = 0; ni < 4; ++ni) b[ni] = Bl[c][kb][wc * 64 + ni * 16 + fr];              \
        _Pragma("unroll")                                                                      \
        for (int mi = 0; mi < 4; ++mi)                                                         \
            _Pragma("unroll")                                                                  \
            for (int ni = 0; ni < 4; ++ni)                                                     \
                acc[mi][ni] = __builtin_amdgcn_mfma_f32_16x16x32_bf16(a[mi], b[ni], acc[mi][ni], 0, 0, 0); \
    }

    STAGE(0, 0);
    __syncthreads();                 // vmcnt(0) drain + barrier: buf0 ready
    int cur = 0;
    for (int k0 = 32; k0 < Dd; k0 += 32) {
        STAGE(cur ^ 1, k0);          // next-tile loads fly under compute
        COMPUTE(cur);
        __syncthreads();             // drains vmcnt(0): next buf ready, cur reusable
        cur ^= 1;
    }
    COMPUTE(cur);
#undef STAGE
#undef COMPUTE

    // C/D layout: col = lane&15, row = (lane>>4)*4 + r   [verified m89/m91]
    const int r0 = mBase + wr * 64 + kb * 4;
    const int c0 = nBase + wc * 64 + fr;
#pragma unroll
    for (int mi = 0; mi < 4; ++mi)
#pragma unroll
        for (int ni = 0; ni < 4; ++ni)
#pragma unroll
            for (int r = 0; r < 4; ++r)
                proj[(size_t)(r0 + mi * 16 + r) * NPAD + c0 + ni * 16] = f2bf(acc[mi][ni][r]);
}

// -------------------------------------------------------------------------
// Kernel 3: per-pair tanh + 300x4 matvec + softmax. ONE WAVE PER PAIR
// (32768 waves: latency-bound gather needs max TLP — R5 lesson).
// -------------------------------------------------------------------------
__global__ __launch_bounds__(256) void mlp_kernel(
    const unsigned short* __restrict__ proj, const float* __restrict__ b1,
    const float* __restrict__ w2, const float* __restrict__ b2,
    const int* __restrict__ pair_idx, float* __restrict__ out)
{
    const int wid  = (int)((blockIdx.x * blockDim.x + threadIdx.x) >> 6);  // pair id
    const int lane = threadIdx.x & 63;
    if (wid >= Bb * Pp) return;

    const int b  = wid >> 10;
    const int i0 = pair_idx[wid * 2 + 0];
    const int i1 = pair_idx[wid * 2 + 1];
    const unsigned short* r0 = (i0 >= 0) ? proj + ((size_t)(b * Ww + i0) * NPAD)      : nullptr;
    const unsigned short* r1 = (i1 >= 0) ? proj + ((size_t)(b * Ww + i1) * NPAD + NH) : nullptr;

    float a0 = 0.f, a1 = 0.f, a2 = 0.f, a3 = 0.f;
#pragma unroll
    for (int it = 0; it < 5; ++it) {
        const int j = lane + it * 64;
        if (j < NH) {
            float v = b1[j];
            if (r0) v += bf2f(r0[j]);
            if (r1) v += bf2f(r1[j]);
            const float x = fast_tanh(v);
            const float4 wv = *(const float4*)(w2 + (size_t)j * 4);
            a0 = fmaf(x, wv.x, a0);
            a1 = fmaf(x, wv.y, a1);
            a2 = fmaf(x, wv.z, a2);
            a3 = fmaf(x, wv.w, a3);
        }
    }
#pragma unroll
    for (int off = 32; off >= 1; off >>= 1) {
        a0 += __shfl_xor(a0, off, 64);
        a1 += __shfl_xor(a1, off, 64);
        a2 += __shfl_xor(a2, off, 64);
        a3 += __shfl_xor(a3, off, 64);
    }
    if (lane == 0) {
        const float l0 = a0 + b2[0], l1 = a1 + b2[1], l2 = a2 + b2[2], l3 = a3 + b2[3];
        const float mx = fmaxf(fmaxf(l0, l1), fmaxf(l2, l3));
        const float e0 = __expf(l0 - mx), e1 = __expf(l1 - mx);
        const float e2 = __expf(l2 - mx), e3 = __expf(l3 - mx);
        const float inv = 1.0f / (e0 + e1 + e2 + e3);
        float4 o = {e0 * inv, e1 * inv, e2 * inv, e3 * inv};
        *(float4*)(out + (size_t)wid * 4) = o;
    }
}

// -------------------------------------------------------------------------
extern "C" void kernel_launch(void* const* d_in, const int* in_sizes, int n_in,
                              void* d_out, int out_size, void* d_ws, size_t ws_size,
                              hipStream_t stream)
{
    const float* h          = (const float*)d_in[0];
    const float* w1         = (const float*)d_in[1];
    const float* b1         = (const float*)d_in[2];
    const float* w2         = (const float*)d_in[3];
    const float* b2         = (const float*)d_in[4];
    const int*   word_start = (const int*)d_in[5];
    const int*   word_len   = (const int*)d_in[6];
    const int*   pair_idx   = (const int*)d_in[7];
    float*       out        = (float*)d_out;

    // workspace layout (all bf16)
    unsigned short* proj  = (unsigned short*)d_ws;                        // 10,485,760 B
    unsigned short* emb   = (unsigned short*)((char*)d_ws + 10485760);    // 12,582,912 B
    unsigned short* bmatT = (unsigned short*)((char*)d_ws + 10485760 + 12582912); // 983,040 B

    prep_kernel<<<dim3(Mm + 4 * NPAD), dim3(192), 0, stream>>>(h, w1, word_start, word_len, emb, bmatT);
    gemm_kernel<<<dim3(320), dim3(256), 0, stream>>>(emb, bmatT, proj);
    mlp_kernel <<<dim3(8192), dim3(256), 0, stream>>>(proj, b1, w2, b2, pair_idx, out);
}

// Round 7
// 53.594 us; speedup vs baseline: 5.6485x; 1.1918x over previous
//
#include <hip/hip_runtime.h>
#include <cstddef>
#include <cstdint>

// Problem constants
#define Bb   32
#define Ss   512
#define Dd   768
#define Ww   256
#define Pp   1024
#define NH   300          // hidden
#define SLOT1 320         // slot-1 column base (128B-aligned: 320*2B = 640B)
#define NPAD 640          // padded proj row: [0,300) slot0, [320,620) slot1
#define Mm   (Bb * Ww)    // 8192 words

typedef __attribute__((ext_vector_type(8))) short bf16x8;
typedef __attribute__((ext_vector_type(4))) float f32x4;

#define GPTR(p) ((const __attribute__((address_space(1))) void*)(p))
#define LPTR(p) ((__attribute__((address_space(3))) void*)(p))

__device__ __forceinline__ unsigned short f2bf(float x) {
    unsigned u = __builtin_bit_cast(unsigned, x);
    u += 0x7fffu + ((u >> 16) & 1u);          // RNE
    return (unsigned short)(u >> 16);
}
__device__ __forceinline__ float bf2f(unsigned short u) {
    return __builtin_bit_cast(float, (unsigned)u << 16);
}
__device__ __forceinline__ float fast_tanh(float x) {
    // tanh(x) = 1 - 2/(exp(2x)+1); clamp so exp never overflows
    x = fminf(fmaxf(x, -15.0f), 15.0f);
    float e = __expf(2.0f * x);
    return 1.0f - 2.0f * __builtin_amdgcn_rcpf(e + 1.0f);
}

// -------------------------------------------------------------------------
// Kernel 1 (prep): blocks [0, 8192): mean-pool h -> emb bf16 (one word/block)
//                  blocks [8192, 8192+2560): repack w1 -> BmatT bf16
//                  block  8192+2560: zero the dummy gather row
//   BmatT[n][k] = n<300 ? w1[k][n] : (320<=n<620 ? w1[768+k][n-320] : 0)
// -------------------------------------------------------------------------
__global__ __launch_bounds__(192) void prep_kernel(
    const float* __restrict__ h, const float* __restrict__ w1,
    const int* __restrict__ word_start, const int* __restrict__ word_len,
    unsigned short* __restrict__ emb, unsigned short* __restrict__ bmatT,
    unsigned short* __restrict__ zrow)
{
    const int bid = blockIdx.x;
    const int t   = threadIdx.x;      // 0..191
    if (bid < Mm) {
        const int m   = bid;
        const int b   = m >> 8;
        const int s0  = word_start[m];
        const int len = word_len[m];
        const float* p = h + (size_t)b * (Ss * Dd) + (size_t)s0 * Dd + t * 4;
        float4 v = *(const float4*)p;
        if (len == 2) {
            float4 v2 = *(const float4*)(p + Dd);
            v.x = (v.x + v2.x) * 0.5f;
            v.y = (v.y + v2.y) * 0.5f;
            v.z = (v.z + v2.z) * 0.5f;
            v.w = (v.w + v2.w) * 0.5f;
        }
        ushort4 o = make_ushort4(f2bf(v.x), f2bf(v.y), f2bf(v.z), f2bf(v.w));
        *(ushort4*)(emb + (size_t)m * Dd + t * 4) = o;
    } else if (bid < Mm + 4 * NPAD) {
        const int rb = bid - Mm;
        const int n  = rb >> 2;                 // 0..639
        const int k  = ((rb & 3) * 192) + t;    // 0..767
        float v = 0.0f;
        if (n < NH)                          v = w1[(size_t)k * NH + n];
        else if (n >= SLOT1 && n < SLOT1+NH) v = w1[(size_t)(Dd + k) * NH + (n - SLOT1)];
        bmatT[(size_t)n * Dd + k] = f2bf(v);
    } else {
        // zero dummy row (NPAD ushorts) for invalid pair slots
        if (t < NPAD / 4)
            *(ushort4*)(zrow + t * 4) = make_ushort4(0, 0, 0, 0);
    }
}

// -------------------------------------------------------------------------
// Kernel 2: MFMA bf16 GEMM: proj[8192][640] = emb[8192][768] @ Bmat[768][640]
// Tile 128x128, BK=32, 256 threads = 4 waves (2x2), each wave 64x64 (4x4).
// Double-buffered LDS (2-phase). Bijective XCD swizzle (320 = 8*40).
// (UNCHANGED from R5 — clean A/B vs the new mlp.)
// -------------------------------------------------------------------------
__global__ __launch_bounds__(256) void gemm_kernel(
    const unsigned short* __restrict__ emb, const unsigned short* __restrict__ bmatT,
    unsigned short* __restrict__ proj)
{
    __shared__ bf16x8 Al[2][4][128];   // 16 KB
    __shared__ bf16x8 Bl[2][4][128];   // 16 KB

    const int bid = blockIdx.x;
    const int t   = threadIdx.x;

    const int swz   = (bid & 7) * 40 + (bid >> 3);
    const int mBase = (swz / 5) * 128;
    const int nBase = (swz % 5) * 128;

    const int srow = t & 127;
    const int skb  = t >> 7;
    const unsigned short* srcA = emb   + (size_t)(mBase + srow) * Dd + (skb << 3);
    const unsigned short* srcB = bmatT + (size_t)(nBase + srow) * Dd + (skb << 3);
    char* ldsA = (char*)&Al[0][0][0] + t * 16;
    char* ldsB = (char*)&Bl[0][0][0] + t * 16;

    const int lane = t & 63;
    const int w    = t >> 6;
    const int wr   = w >> 1;
    const int wc   = w & 1;
    const int fr   = lane & 15;
    const int kb   = lane >> 4;

    f32x4 acc[4][4];
#pragma unroll
    for (int i = 0; i < 4; ++i)
#pragma unroll
        for (int j = 0; j < 4; ++j)
#pragma unroll
            for (int r = 0; r < 4; ++r) acc[i][j][r] = 0.0f;

#define STAGE(c, off)                                                                          \
    __builtin_amdgcn_global_load_lds(GPTR(srcA + (off)),      LPTR(ldsA + (c) * 8192),        16, 0, 0); \
    __builtin_amdgcn_global_load_lds(GPTR(srcA + (off) + 16), LPTR(ldsA + (c) * 8192 + 4096), 16, 0, 0); \
    __builtin_amdgcn_global_load_lds(GPTR(srcB + (off)),      LPTR(ldsB + (c) * 8192),        16, 0, 0); \
    __builtin_amdgcn_global_load_lds(GPTR(srcB + (off) + 16), LPTR(ldsB + (c) * 8192 + 4096), 16, 0, 0)

#define COMPUTE(c)                                                                             \
    {                                                                                          \
        bf16x8 a[4], b[4];                                                                     \
        _Pragma("unroll")                                                                      \
        for (int mi = 0; mi < 4; ++mi) a[mi] = Al[c][kb][wr * 64 + mi * 16 + fr];              \
        _Pragma("unroll")                                                                      \
        for (int ni = 0; ni < 4; ++ni) b[ni] = Bl[c][kb][wc * 64 + ni * 16 + fr];              \
        _Pragma("unroll")                                                                      \
        for (int mi = 0; mi < 4; ++mi)                                                         \
            _Pragma("unroll")                                                                  \
            for (int ni = 0; ni < 4; ++ni)                                                     \
                acc[mi][ni] = __builtin_amdgcn_mfma_f32_16x16x32_bf16(a[mi], b[ni], acc[mi][ni], 0, 0, 0); \
    }

    STAGE(0, 0);
    __syncthreads();
    int cur = 0;
    for (int k0 = 32; k0 < Dd; k0 += 32) {
        STAGE(cur ^ 1, k0);
        COMPUTE(cur);
        __syncthreads();
        cur ^= 1;
    }
    COMPUTE(cur);
#undef STAGE
#undef COMPUTE

    const int r0 = mBase + wr * 64 + kb * 4;
    const int c0 = nBase + wc * 64 + fr;
#pragma unroll
    for (int mi = 0; mi < 4; ++mi)
#pragma unroll
        for (int ni = 0; ni < 4; ++ni)
#pragma unroll
            for (int r = 0; r < 4; ++r)
                proj[(size_t)(r0 + mi * 16 + r) * NPAD + c0 + ni * 16] = f2bf(acc[mi][ni][r]);
}

// -------------------------------------------------------------------------
// Kernel 3: per-pair tanh + 300x4 matvec + softmax. 4 PAIRS PER WAVE:
// all 40 gathers issued unconditionally up front (invalid slots -> zrow)
// for deep memory-level parallelism; softmax finished on lanes 0..3.
// -------------------------------------------------------------------------
__global__ __launch_bounds__(256) void mlp_kernel(
    const unsigned short* __restrict__ proj, const unsigned short* __restrict__ zrow,
    const float* __restrict__ b1, const float* __restrict__ w2,
    const float* __restrict__ b2, const int* __restrict__ pair_idx,
    float* __restrict__ out)
{
    const int wave = blockIdx.x * 4 + (threadIdx.x >> 6);   // 0..8191
    const int lane = threadIdx.x & 63;
    const int wid0 = wave * 4;                              // 4 pairs, same batch
    const int b    = wid0 >> 10;

    const int4 piA = *(const int4*)(pair_idx + wid0 * 2);
    const int4 piB = *(const int4*)(pair_idx + wid0 * 2 + 4);
    const int idx[8] = {piA.x, piA.y, piA.z, piA.w, piB.x, piB.y, piB.z, piB.w};

    const unsigned short* base = proj + (size_t)b * (Ww * NPAD);

    // row pointers: invalid slot -> zero row (keeps loads unconditional)
    const unsigned short* r0p[4];
    const unsigned short* r1p[4];
#pragma unroll
    for (int p = 0; p < 4; ++p) {
        const int i0 = idx[p * 2], i1 = idx[p * 2 + 1];
        r0p[p] = (i0 >= 0) ? base + (size_t)i0 * NPAD : zrow;
        r1p[p] = ((i1 >= 0) ? base + (size_t)i1 * NPAD : zrow) + SLOT1;
    }

    // issue all 40 gathers (independent -> one big clause)
    unsigned short g0[4][5], g1[4][5];
#pragma unroll
    for (int p = 0; p < 4; ++p)
#pragma unroll
        for (int it = 0; it < 5; ++it) {
            const int j = lane + it * 64;     // j<320 always; cols [300,320) are zero
            g0[p][it] = r0p[p][j];
            g1[p][it] = r1p[p][j];
        }

    float acc[4][4];
#pragma unroll
    for (int p = 0; p < 4; ++p)
#pragma unroll
        for (int c = 0; c < 4; ++c) acc[p][c] = 0.0f;

#pragma unroll
    for (int it = 0; it < 5; ++it) {
        const int j  = lane + it * 64;
        const bool ok = (j < NH);             // divergent only at it=4
        const float bj = ok ? b1[j] : 0.0f;
        float4 wv = make_float4(0.f, 0.f, 0.f, 0.f);
        if (ok) wv = *(const float4*)(w2 + (size_t)j * 4);
#pragma unroll
        for (int p = 0; p < 4; ++p) {
            const float v = bj + bf2f(g0[p][it]) + bf2f(g1[p][it]);
            const float x = ok ? fast_tanh(v) : 0.0f;
            acc[p][0] = fmaf(x, wv.x, acc[p][0]);
            acc[p][1] = fmaf(x, wv.y, acc[p][1]);
            acc[p][2] = fmaf(x, wv.z, acc[p][2]);
            acc[p][3] = fmaf(x, wv.w, acc[p][3]);
        }
    }

    // butterfly reduce: afterwards every lane holds all 16 sums
#pragma unroll
    for (int off = 32; off >= 1; off >>= 1)
#pragma unroll
        for (int p = 0; p < 4; ++p)
#pragma unroll
            for (int c = 0; c < 4; ++c)
                acc[p][c] += __shfl_xor(acc[p][c], off, 64);

    // lane p (p<4) finishes pair p's softmax (static register indexing)
    float l0 = 0.f, l1 = 0.f, l2 = 0.f, l3 = 0.f;
#pragma unroll
    for (int p = 0; p < 4; ++p)
        if (lane == p) { l0 = acc[p][0]; l1 = acc[p][1]; l2 = acc[p][2]; l3 = acc[p][3]; }

    if (lane < 4) {
        l0 += b2[0]; l1 += b2[1]; l2 += b2[2]; l3 += b2[3];
        const float mx = fmaxf(fmaxf(l0, l1), fmaxf(l2, l3));
        const float e0 = __expf(l0 - mx), e1 = __expf(l1 - mx);
        const float e2 = __expf(l2 - mx), e3 = __expf(l3 - mx);
        const float inv = 1.0f / (e0 + e1 + e2 + e3);
        float4 o = {e0 * inv, e1 * inv, e2 * inv, e3 * inv};
        *(float4*)(out + (size_t)(wid0 + lane) * 4) = o;
    }
}

// -------------------------------------------------------------------------
extern "C" void kernel_launch(void* const* d_in, const int* in_sizes, int n_in,
                              void* d_out, int out_size, void* d_ws, size_t ws_size,
                              hipStream_t stream)
{
    const float* h          = (const float*)d_in[0];
    const float* w1         = (const float*)d_in[1];
    const float* b1         = (const float*)d_in[2];
    const float* w2         = (const float*)d_in[3];
    const float* b2         = (const float*)d_in[4];
    const int*   word_start = (const int*)d_in[5];
    const int*   word_len   = (const int*)d_in[6];
    const int*   pair_idx   = (const int*)d_in[7];
    float*       out        = (float*)d_out;

    // workspace layout (all bf16)
    unsigned short* proj  = (unsigned short*)d_ws;                         // 10,485,760 B
    unsigned short* emb   = (unsigned short*)((char*)d_ws + 10485760);     // 12,582,912 B
    unsigned short* bmatT = (unsigned short*)((char*)d_ws + 23068672);     // 983,040 B
    unsigned short* zrow  = (unsigned short*)((char*)d_ws + 24051712);     // 1,280 B

    prep_kernel<<<dim3(Mm + 4 * NPAD + 1), dim3(192), 0, stream>>>(
        h, w1, word_start, word_len, emb, bmatT, zrow);
    gemm_kernel<<<dim3(320), dim3(256), 0, stream>>>(emb, bmatT, proj);
    mlp_kernel <<<dim3(2048), dim3(256), 0, stream>>>(proj, zrow, b1, w2, b2, pair_idx, out);
}